// Round 11
// baseline (512.613 us; speedup 1.0000x reference)
//
#include <hip/hip_runtime.h>
#include <math.h>

#define DIM 128
#define HEADS 4
#define EPS 1e-5f
#define NBLK 2048

// ---------- dtype-flex helpers ----------
__device__ __forceinline__ float us2f(unsigned short u) {
  union { unsigned int i; float f; } c; c.i = ((unsigned int)u) << 16; return c.f;
}
__device__ __forceinline__ unsigned short f2us(float f) {
  union { float ff; unsigned int i; } c; c.ff = f;
  return (unsigned short)((c.i + 0x7FFFu + ((c.i >> 16) & 1u)) >> 16);
}
__device__ __forceinline__ float ldf(const void* p, size_t i, int fl32) {
  return fl32 ? ((const float*)p)[i] : us2f(((const unsigned short*)p)[i]);
}
__device__ __forceinline__ float gelu_exact(float v) {
  return 0.5f * v * (1.0f + erff(v * 0.7071067811865475f));
}
__device__ __forceinline__ int imin(int a, int b) { return a < b ? a : b; }

// ---------- dtype detection (proven) ----------
__global__ void __launch_bounds__(256)
k_detect(const unsigned short* __restrict__ x, long n, int* __restrict__ dflag) {
  long lim = n < 8192 ? n : 8192;
  int bad = 0;
  for (long i = threadIdx.x; i < lim; i += 256) {
    float v = us2f(x[i]);
    float a = fabsf(v);
    if (!(a == 0.0f || (a > 1e-30f && a < 1e3f))) bad++;
  }
  __shared__ int sb[256];
  sb[threadIdx.x] = bad;
  __syncthreads();
  for (int off = 128; off > 0; off >>= 1) {
    if ((int)threadIdx.x < off) sb[threadIdx.x] += sb[threadIdx.x + off];
    __syncthreads();
  }
  if (threadIdx.x == 0) dflag[0] = (sb[0] > 32) ? 1 : 0;
}

// ---------- CSR construction (atomic-light; R7-proven) ----------
__global__ void k_cnt(const int* __restrict__ dst, int* __restrict__ cnt,
                      int* __restrict__ rank, int E) {
  int e = blockIdx.x * blockDim.x + threadIdx.x;
  if (e < E) rank[e] = atomicAdd(&cnt[dst[e]], 1);
}

__global__ void __launch_bounds__(256)
k_scan(const int* __restrict__ cnt, int* __restrict__ off, int N, int E) {
  __shared__ int part[256];
  int t = threadIdx.x;
  int chunk = (N + 255) / 256;
  int lo = t * chunk;
  int hi = lo + chunk; if (hi > N) hi = N;
  int s = 0;
  for (int i = lo; i < hi; ++i) s += cnt[i];
  part[t] = s;
  __syncthreads();
  if (t == 0) {
    int run = 0;
    for (int j = 0; j < 256; ++j) { int tmp = part[j]; part[j] = run; run += tmp; }
  }
  __syncthreads();
  int run = part[t];
  for (int i = lo; i < hi; ++i) { off[i] = run; run += cnt[i]; }
  if (t == 0) off[N] = E;
}

// csr record: (src, w_raw, eav, dst); nm is computed in k_mega's staging
__global__ void k_scatter(const int* __restrict__ src, const int* __restrict__ dst,
                          const void* __restrict__ ew, const void* __restrict__ ea,
                          const int* __restrict__ off, const int* __restrict__ rank,
                          int4* __restrict__ csr, int E, const int* __restrict__ df) {
  const int fl32 = *df;
  int e = blockIdx.x * blockDim.x + threadIdx.x;
  if (e >= E) return;
  int d = dst[e], s = src[e];
  int pos = off[d] + rank[e];
  float w = ldf(ew, e, fl32);
  float eav = ldf(ea, e, fl32);
  if (!isfinite(eav)) eav = 0.0f;
  csr[pos] = make_int4(s, __float_as_int(w), __float_as_int(eav), d);
}

// per-node ordered segment sum of w + fused rsqrt. csr is L2/L3-resident.
__global__ void k_degdis(const int* __restrict__ off, const int4* __restrict__ csr,
                         float* __restrict__ dis, int N) {
  int i = blockIdx.x * blockDim.x + threadIdx.x;
  if (i >= N) return;
  int b = off[i], t = off[i + 1];
  float s = 0.f;
  for (int j = b; j < t; ++j) {
    float w = __int_as_float(csr[j].y);
    if (isfinite(w)) s += w;
  }
  dis[i] = (s > 0.0f) ? rsqrtf(fmaxf(s, 1e-30f)) : 0.0f;
}

// ---------- MFMA dual-GEMM prep ----------
// B2T[col][k] bf16 col-major, columns pre-permuted to packed-row order;
// hi/lo split of B (3xBF16) keeps GEMM at ~fp32 accuracy.
__global__ void __launch_bounds__(256)
k_wprep(const void* __restrict__ Wg, const void* __restrict__ Wl,
        const void* __restrict__ bl, unsigned short* __restrict__ Bhi,
        unsigned short* __restrict__ Blo, float* __restrict__ bias2,
        const int* __restrict__ df) {
  const int fl32 = *df;
  int g = blockIdx.x * 256 + threadIdx.x;   // 0 .. 32767
  int col = g >> 7, k = g & 127;
  int t4 = col >> 2, r = col & 3;
  int wcol = t4 * 2 + (r & 1);
  float v = (r < 2) ? ldf(Wl, (size_t)k * DIM + wcol, fl32)
                    : ldf(Wg, (size_t)k * DIM + wcol, fl32);
  unsigned short hi = f2us(v);
  float lo = v - us2f(hi);
  Bhi[(size_t)col * 128 + k] = hi;
  Blo[(size_t)col * 128 + k] = f2us(lo);
  if (blockIdx.x == 0) {
    int c2 = threadIdx.x;
    int tt = c2 >> 2, rr = c2 & 3;
    bias2[c2] = (rr < 2) ? ldf(bl, tt * 2 + rr, fl32) : 0.0f;
  }
}

typedef __attribute__((ext_vector_type(8))) short short8v;          // 8 bf16
typedef __attribute__((ext_vector_type(4))) float f32x4;            // MFMA acc

// 64 rows x 256 cols per block; 4 waves. bf16 fast-path: residuals exactly
// zero -> skip lo staging AND lo MFMAs (wave-uniform branch).
__global__ void __launch_bounds__(256)
k_gemm_mfma(const void* __restrict__ x, const unsigned short* __restrict__ Bhi,
            const unsigned short* __restrict__ Blo, const float* __restrict__ bias2,
            unsigned short* __restrict__ packed, int N, const int* __restrict__ df) {
  const int fl32 = *df;
  __shared__ unsigned short Ahi[64 * 128];
  __shared__ unsigned short Alo[64 * 128];
  const int tid = threadIdx.x;
  const int r0 = blockIdx.x * 64;
  if (fl32) {
    #pragma unroll
    for (int it = 0; it < 8; ++it) {
      int i4 = tid + it * 256;
      int row = i4 >> 5, kq = i4 & 31;
      int grow = r0 + row;
      float v0 = 0.f, v1 = 0.f, v2 = 0.f, v3 = 0.f;
      if (grow < N) {
        float4 f = ((const float4*)x)[(size_t)grow * 32 + kq];
        v0 = f.x; v1 = f.y; v2 = f.z; v3 = f.w;
      }
      ushort4 hi = make_ushort4(f2us(v0), f2us(v1), f2us(v2), f2us(v3));
      ushort4 lo = make_ushort4(f2us(v0 - us2f(hi.x)), f2us(v1 - us2f(hi.y)),
                                f2us(v2 - us2f(hi.z)), f2us(v3 - us2f(hi.w)));
      int ba = (row * 256 + kq * 8) ^ ((row & 7) << 4);
      *(ushort4*)((char*)Ahi + ba) = hi;
      *(ushort4*)((char*)Alo + ba) = lo;
    }
  } else {
    #pragma unroll
    for (int it = 0; it < 8; ++it) {
      int i4 = tid + it * 256;
      int row = i4 >> 5, kq = i4 & 31;
      int grow = r0 + row;
      ushort4 hi = make_ushort4(0, 0, 0, 0);
      if (grow < N) hi = ((const ushort4*)x)[(size_t)grow * 32 + kq];
      int ba = (row * 256 + kq * 8) ^ ((row & 7) << 4);
      *(ushort4*)((char*)Ahi + ba) = hi;
    }
  }
  __syncthreads();
  const int lane = tid & 63, wid = tid >> 6;
  const int mbase = (wid >> 1) * 32;
  const int nbase = (wid & 1) * 128;
  const int lr = lane & 15, lk = lane >> 4;
  short8v ah[2][4];
  #pragma unroll
  for (int m = 0; m < 2; ++m) {
    #pragma unroll
    for (int ks = 0; ks < 4; ++ks) {
      int row = mbase + m * 16 + lr;
      int ba = (row * 256 + ks * 64 + lk * 16) ^ ((row & 7) << 4);
      ah[m][ks] = *(const short8v*)((const char*)Ahi + ba);
    }
  }
  f32x4 acc[2][8];
  const f32x4 zero = {0.0f, 0.0f, 0.0f, 0.0f};
  #pragma unroll
  for (int m = 0; m < 2; ++m)
    #pragma unroll
    for (int n = 0; n < 8; ++n) acc[m][n] = zero;
  if (fl32) {
    short8v al[2][4];
    #pragma unroll
    for (int m = 0; m < 2; ++m) {
      #pragma unroll
      for (int ks = 0; ks < 4; ++ks) {
        int row = mbase + m * 16 + lr;
        int ba = (row * 256 + ks * 64 + lk * 16) ^ ((row & 7) << 4);
        al[m][ks] = *(const short8v*)((const char*)Alo + ba);
      }
    }
    #pragma unroll
    for (int n = 0; n < 8; ++n) {
      int col = nbase + n * 16 + lr;
      const unsigned short* bh0 = Bhi + (size_t)col * 128 + lk * 8;
      const unsigned short* bl0 = Blo + (size_t)col * 128 + lk * 8;
      #pragma unroll
      for (int ks = 0; ks < 4; ++ks) {
        short8v bh  = *(const short8v*)(bh0 + ks * 32);
        short8v blv = *(const short8v*)(bl0 + ks * 32);
        acc[0][n] = __builtin_amdgcn_mfma_f32_16x16x32_bf16(ah[0][ks], bh, acc[0][n], 0, 0, 0);
        acc[1][n] = __builtin_amdgcn_mfma_f32_16x16x32_bf16(ah[1][ks], bh, acc[1][n], 0, 0, 0);
        acc[0][n] = __builtin_amdgcn_mfma_f32_16x16x32_bf16(al[0][ks], bh, acc[0][n], 0, 0, 0);
        acc[1][n] = __builtin_amdgcn_mfma_f32_16x16x32_bf16(al[1][ks], bh, acc[1][n], 0, 0, 0);
        acc[0][n] = __builtin_amdgcn_mfma_f32_16x16x32_bf16(ah[0][ks], blv, acc[0][n], 0, 0, 0);
        acc[1][n] = __builtin_amdgcn_mfma_f32_16x16x32_bf16(ah[1][ks], blv, acc[1][n], 0, 0, 0);
      }
    }
  } else {
    #pragma unroll
    for (int n = 0; n < 8; ++n) {
      int col = nbase + n * 16 + lr;
      const unsigned short* bh0 = Bhi + (size_t)col * 128 + lk * 8;
      #pragma unroll
      for (int ks = 0; ks < 4; ++ks) {
        short8v bh = *(const short8v*)(bh0 + ks * 32);
        acc[0][n] = __builtin_amdgcn_mfma_f32_16x16x32_bf16(ah[0][ks], bh, acc[0][n], 0, 0, 0);
        acc[1][n] = __builtin_amdgcn_mfma_f32_16x16x32_bf16(ah[1][ks], bh, acc[1][n], 0, 0, 0);
      }
    }
  }
  #pragma unroll
  for (int m = 0; m < 2; ++m) {
    #pragma unroll
    for (int n = 0; n < 8; ++n) {
      int col = nbase + n * 16 + lr;
      float bv = bias2[col];
      int rb = r0 + mbase + m * 16 + lk * 4;
      #pragma unroll
      for (int j = 0; j < 4; ++j) {
        int row = rb + j;
        if (row < N) {
          float v = acc[m][n][j] + bv;
          if (!isfinite(v)) v = 0.0f;
          packed[(size_t)row * 256 + col] = f2us(v);
        }
      }
    }
  }
}

// ---------- MEGA: online softmax + GCN/GAT agg + LN stats ----------
// R4-proven processing structure (105us): LDS-staged csr metadata window +
// 8-slot rotating clamped register prefetch (bracketed optimum 1/8/12 =
// 132/105/123). nm computed during staging (R10), but NOW the csr load and
// dis gathers are software-pipelined: first window issued BEFORE any barrier
// (overlaps off/xd/param loads); subsequent windows' csr issued between the
// staging barriers, dis gathers issued after the processing phase. Same fp32
// ops/order => bit-identical results.
#define GATHER(sidx) (*(const ushort4*)(packed + (size_t)(sidx) * 256 + lane * 4))

#define PROC(v, m) {                                                       \
  float nm = __int_as_float((m).y), eav = __int_as_float((m).z);           \
  float vx = us2f((v).x), vy = us2f((v).y);                                \
  float z0 = xd0 + vx + eav * wd0; z0 = (z0 > 0.f) ? z0 : 0.2f * z0;       \
  float z1 = xd1 + vy + eav * wd1; z1 = (z1 > 0.f) ? z1 : 0.2f * z1;       \
  float dt = z0 * at0 + z1 * at1;                                          \
  dt += __shfl_xor(dt, 1);                                                 \
  dt += __shfl_xor(dt, 2);                                                 \
  dt += __shfl_xor(dt, 4);                                                 \
  dt += __shfl_xor(dt, 8);                                                 \
  float e = __expf(-fabsf(dt - mx));                                       \
  bool up = dt > mx;                                                       \
  float corr = up ? e : 1.0f;                                              \
  float w = up ? 1.0f : e;                                                 \
  mx = up ? dt : mx;                                                       \
  den = fmaf(den, corr, w);                                                \
  ga0 = fmaf(ga0, corr, w * vx);                                           \
  ga1 = fmaf(ga1, corr, w * vy);                                           \
  hc0 = fmaf(nm, us2f((v).z), hc0);                                        \
  hc1 = fmaf(nm, us2f((v).w), hc1);                                        \
}

__global__ void __launch_bounds__(256)
k_mega(const int* __restrict__ off, const int4* __restrict__ csr,
       const float* __restrict__ dis,
       const unsigned short* __restrict__ packed,
       const void* __restrict__ Wed, const void* __restrict__ att,
       const void* __restrict__ bgcn, const void* __restrict__ bgat,
       float* __restrict__ h, float* __restrict__ g,
       double* __restrict__ pA, double* __restrict__ pB, int N,
       const int* __restrict__ df) {
  const int fl32 = *df;
  const int tid = threadIdx.x;
  const int wid = tid >> 6;
  const int lane = tid & 63;
  const int n0 = blockIdx.x * 4;
  const int node = n0 + wid;
  const int c0 = lane * 2;

  const int blkBeg = off[n0];
  const int nTop = (n0 + 4 < N) ? (n0 + 4) : N;
  const int blkEnd = off[nTop];

  // ---- prologue prefetch: first window's csr + dis, before any barrier ----
  int4 c_cur = make_int4(0, 0, 0, 0);
  float dsrc = 0.f, ddst = 0.f;
  {
    int wlen0 = blkEnd - blkBeg; if (wlen0 > 256) wlen0 = 256;
    if (tid < wlen0) {
      c_cur = csr[blkBeg + tid];
      dsrc = dis[c_cur.x];
      ddst = dis[c_cur.w];
    }
  }

  float wd0 = ldf(Wed, c0, fl32), wd1 = ldf(Wed, c0 + 1, fl32);
  float at0 = ldf(att, c0, fl32), at1 = ldf(att, c0 + 1, fl32);

  int beg = 0, end = 0;
  float xd0 = 0.f, xd1 = 0.f;
  if (node < N) {
    beg = off[node]; end = off[node + 1];
    ushort4 xd = *(const ushort4*)(packed + (size_t)node * 256 + lane * 4);
    xd0 = us2f(xd.x); xd1 = us2f(xd.y);
  }
  float mx = -INFINITY, den = 0.f;
  float ga0 = 0.f, ga1 = 0.f, hc0 = 0.f, hc1 = 0.f;

  __shared__ int4 smeta[256];

  for (int base = blkBeg; base < blkEnd; base += 256) {
    int wlen = blkEnd - base; if (wlen > 256) wlen = 256;
    __syncthreads();   // prior window's smeta fully consumed
    if (tid < wlen) {
      float nm = dsrc * __int_as_float(c_cur.y) * ddst;
      if (!isfinite(nm)) nm = 0.0f;
      int4 c = c_cur;
      c.y = __float_as_int(nm);
      smeta[tid] = c;
    }
    // issue next window's csr load now; its dis gathers go after processing
    int nbase = base + 256;
    int wlenN = (nbase < blkEnd) ? imin(blkEnd - nbase, 256) : 0;
    int4 c_nxt = make_int4(0, 0, 0, 0);
    if (tid < wlenN) c_nxt = csr[nbase + tid];
    __syncthreads();
    int lo = beg > base ? beg : base;
    int hiEnd = base + wlen;
    int hi = end < hiEnd ? end : hiEnd;
    int cnt = hi - lo;
    if (cnt > 0) {
      int s0 = lo - base;
      int last = s0 + cnt - 1;   // clamp target (always a valid staged edge)
      ushort4 v0, v1, v2, v3, v4, v5, v6, v7;
      v0 = GATHER(smeta[imin(s0 + 0, last)].x);
      v1 = GATHER(smeta[imin(s0 + 1, last)].x);
      v2 = GATHER(smeta[imin(s0 + 2, last)].x);
      v3 = GATHER(smeta[imin(s0 + 3, last)].x);
      v4 = GATHER(smeta[imin(s0 + 4, last)].x);
      v5 = GATHER(smeta[imin(s0 + 5, last)].x);
      v6 = GATHER(smeta[imin(s0 + 6, last)].x);
      v7 = GATHER(smeta[imin(s0 + 7, last)].x);
      int i = 0;
      for (; i + 8 <= cnt; i += 8) {
        int4 m;
        m = smeta[s0 + i + 0]; PROC(v0, m); v0 = GATHER(smeta[imin(s0 + i + 8,  last)].x);
        m = smeta[s0 + i + 1]; PROC(v1, m); v1 = GATHER(smeta[imin(s0 + i + 9,  last)].x);
        m = smeta[s0 + i + 2]; PROC(v2, m); v2 = GATHER(smeta[imin(s0 + i + 10, last)].x);
        m = smeta[s0 + i + 3]; PROC(v3, m); v3 = GATHER(smeta[imin(s0 + i + 11, last)].x);
        m = smeta[s0 + i + 4]; PROC(v4, m); v4 = GATHER(smeta[imin(s0 + i + 12, last)].x);
        m = smeta[s0 + i + 5]; PROC(v5, m); v5 = GATHER(smeta[imin(s0 + i + 13, last)].x);
        m = smeta[s0 + i + 6]; PROC(v6, m); v6 = GATHER(smeta[imin(s0 + i + 14, last)].x);
        m = smeta[s0 + i + 7]; PROC(v7, m); v7 = GATHER(smeta[imin(s0 + i + 15, last)].x);
      }
      if (i < cnt) { int4 m = smeta[s0 + i]; PROC(v0, m); ++i; }
      if (i < cnt) { int4 m = smeta[s0 + i]; PROC(v1, m); ++i; }
      if (i < cnt) { int4 m = smeta[s0 + i]; PROC(v2, m); ++i; }
      if (i < cnt) { int4 m = smeta[s0 + i]; PROC(v3, m); ++i; }
      if (i < cnt) { int4 m = smeta[s0 + i]; PROC(v4, m); ++i; }
      if (i < cnt) { int4 m = smeta[s0 + i]; PROC(v5, m); ++i; }
      if (i < cnt) { int4 m = smeta[s0 + i]; PROC(v6, m); ++i; }
    }
    // set up next window: dis gathers overlap the inter-window barrier
    if (tid < wlenN) {
      c_cur = c_nxt;
      dsrc = dis[c_cur.x];
      ddst = dis[c_cur.w];
    }
  }

  double sA = 0.0, sA2 = 0.0, sB = 0.0, sB2 = 0.0;
  if (node < N) {
    float inv = (end > beg) ? 1.0f / (den + 1e-16f) : 0.0f;
    ga0 *= inv; ga1 *= inv;
    if (!isfinite(ga0)) ga0 = 0.0f;
    if (!isfinite(ga1)) ga1 = 0.0f;
    if (!isfinite(hc0)) hc0 = 0.0f;
    if (!isfinite(hc1)) hc1 = 0.0f;
    *(float2*)(h + (size_t)node * DIM + c0) = make_float2(hc0, hc1);
    *(float2*)(g + (size_t)node * DIM + c0) = make_float2(ga0, ga1);
    float hA0 = hc0 + ldf(bgcn, c0, fl32), hA1 = hc1 + ldf(bgcn, c0 + 1, fl32);
    float gB0 = ga0 + ldf(bgat, c0, fl32), gB1 = ga1 + ldf(bgat, c0 + 1, fl32);
    sA  = (double)hA0 + (double)hA1;
    sA2 = (double)hA0 * hA0 + (double)hA1 * hA1;
    sB  = (double)gB0 + (double)gB1;
    sB2 = (double)gB0 * gB0 + (double)gB1 * gB1;
  }
  __shared__ double l1[256], l2[256], l3[256], l4[256];
  l1[threadIdx.x] = sA; l2[threadIdx.x] = sA2; l3[threadIdx.x] = sB; l4[threadIdx.x] = sB2;
  __syncthreads();
  for (int o = 128; o > 0; o >>= 1) {
    if ((int)threadIdx.x < o) {
      l1[threadIdx.x] += l1[threadIdx.x + o];
      l2[threadIdx.x] += l2[threadIdx.x + o];
      l3[threadIdx.x] += l3[threadIdx.x + o];
      l4[threadIdx.x] += l4[threadIdx.x + o];
    }
    __syncthreads();
  }
  if (threadIdx.x == 0) {
    pA[2 * blockIdx.x] = l1[0]; pA[2 * blockIdx.x + 1] = l2[0];
    pB[2 * blockIdx.x] = l3[0]; pB[2 * blockIdx.x + 1] = l4[0];
  }
}

// ---------- LN finalize / fuse / output ----------
__device__ __forceinline__ void ln_params(double S, double S2, double M, float* mu_out, float* sc_out) {
  double mu = S / M;
  double v = S2 / M - mu * mu;
  if (!(v > 0.0)) v = 0.0;
  float fmu = (float)mu;
  float sc = 1.0f / ((float)sqrt(v) + EPS);
  if (!isfinite(fmu)) fmu = 0.0f;
  if (!isfinite(sc)) sc = 0.0f;
  *mu_out = fmu; *sc_out = sc;
}

__global__ void __launch_bounds__(256)
k_fin12(const double* __restrict__ pA, const double* __restrict__ pB, int nblk,
        const void* __restrict__ alpha, float* __restrict__ params, double M,
        const int* __restrict__ df) {
  const int fl32 = *df;
  __shared__ double l1[256], l2[256], l3[256], l4[256];
  double a = 0, b = 0, c = 0, d = 0;
  for (int j = threadIdx.x; j < nblk; j += 256) {
    a += pA[2 * j]; b += pA[2 * j + 1];
    c += pB[2 * j]; d += pB[2 * j + 1];
  }
  l1[threadIdx.x] = a; l2[threadIdx.x] = b; l3[threadIdx.x] = c; l4[threadIdx.x] = d;
  __syncthreads();
  for (int off = 128; off > 0; off >>= 1) {
    if ((int)threadIdx.x < off) {
      l1[threadIdx.x] += l1[threadIdx.x + off];
      l2[threadIdx.x] += l2[threadIdx.x + off];
      l3[threadIdx.x] += l3[threadIdx.x + off];
      l4[threadIdx.x] += l4[threadIdx.x + off];
    }
    __syncthreads();
  }
  if (threadIdx.x == 0) {
    ln_params(l1[0], l2[0], M, &params[0], &params[1]);
    ln_params(l3[0], l4[0], M, &params[2], &params[3]);
    float a0 = ldf(alpha, 0, fl32), a1 = ldf(alpha, 1, fl32);
    if (!isfinite(a0)) a0 = 0.0f;
    if (!isfinite(a1)) a1 = 0.0f;
    float mx = fmaxf(a0, a1);
    float e0 = expf(a0 - mx), e1 = expf(a1 - mx);
    float inv = 1.0f / (e0 + e1);
    params[4] = e0 * inv;
    params[5] = e1 * inv;
  }
}

__global__ void __launch_bounds__(256)
k_fin3(const double* __restrict__ pC, float* __restrict__ params, double M) {
  __shared__ double l1[256], l2[256];
  double a = 0, b = 0;
  for (int j = threadIdx.x; j < NBLK; j += 256) { a += pC[2 * j]; b += pC[2 * j + 1]; }
  l1[threadIdx.x] = a; l2[threadIdx.x] = b;
  __syncthreads();
  for (int off = 128; off > 0; off >>= 1) {
    if ((int)threadIdx.x < off) {
      l1[threadIdx.x] += l1[threadIdx.x + off];
      l2[threadIdx.x] += l2[threadIdx.x + off];
    }
    __syncthreads();
  }
  if (threadIdx.x == 0) ln_params(l1[0], l2[0], M, &params[6], &params[7]);
}

// vectorized: 4 contiguous elements per thread (float4/ushort4 - G13)
__global__ void __launch_bounds__(256)
k_fuse(const void* __restrict__ x, float* h, const float* __restrict__ g,
       const void* __restrict__ b_gcn, const void* __restrict__ b_gat,
       const void* __restrict__ gcn_nw, const void* __restrict__ gcn_nb,
       const void* __restrict__ gat_nw, const void* __restrict__ gat_nb,
       const float* __restrict__ params, double* __restrict__ pC, long n4,
       const int* __restrict__ df) {
  const int fl32 = *df;
  float mu1 = params[0], sc1 = params[1], mu2 = params[2], sc2 = params[3];
  float w0 = params[4], w1 = params[5];
  double s = 0.0, s2 = 0.0;
  long stride = (long)gridDim.x * blockDim.x;
  for (long i4 = (long)blockIdx.x * blockDim.x + threadIdx.x; i4 < n4; i4 += stride) {
    int c = (int)((i4 * 4) & (DIM - 1));
    float4 hv4 = ((const float4*)h)[i4];
    float4 gv4 = ((const float4*)g)[i4];
    float xv[4];
    if (fl32) {
      float4 xf = ((const float4*)x)[i4];
      xv[0] = xf.x; xv[1] = xf.y; xv[2] = xf.z; xv[3] = xf.w;
    } else {
      ushort4 xu = ((const ushort4*)x)[i4];
      xv[0] = us2f(xu.x); xv[1] = us2f(xu.y); xv[2] = us2f(xu.z); xv[3] = us2f(xu.w);
    }
    float hv[4] = {hv4.x, hv4.y, hv4.z, hv4.w};
    float gv[4] = {gv4.x, gv4.y, gv4.z, gv4.w};
    float fo[4];
    #pragma unroll
    for (int j = 0; j < 4; ++j) {
      int cj = c + j;
      float hb = hv[j] + ldf(b_gcn, cj, fl32);
      float gb = gv[j] + ldf(b_gat, cj, fl32);
      float go = xv[j] + gelu_exact((hb - mu1) * sc1 * ldf(gcn_nw, cj, fl32) + ldf(gcn_nb, cj, fl32));
      float ao = xv[j] + gelu_exact((gb - mu2) * sc2 * ldf(gat_nw, cj, fl32) + ldf(gat_nb, cj, fl32));
      float f = w0 * go + w1 * ao;
      if (!isfinite(f)) f = 0.0f;
      fo[j] = f;
      s += f; s2 += (double)f * f;
    }
    ((float4*)h)[i4] = make_float4(fo[0], fo[1], fo[2], fo[3]);
  }
  __shared__ double ls[256], ls2[256];
  ls[threadIdx.x] = s; ls2[threadIdx.x] = s2;
  __syncthreads();
  for (int off = 128; off > 0; off >>= 1) {
    if ((int)threadIdx.x < off) {
      ls[threadIdx.x] += ls[threadIdx.x + off];
      ls2[threadIdx.x] += ls2[threadIdx.x + off];
    }
    __syncthreads();
  }
  if (threadIdx.x == 0) { pC[2 * blockIdx.x] = ls[0]; pC[2 * blockIdx.x + 1] = ls2[0]; }
}

__global__ void k_final(const float* __restrict__ fused, const void* __restrict__ nw,
                        const void* __restrict__ nb, const float* __restrict__ params,
                        void* __restrict__ out, long n4, const int* __restrict__ df) {
  const int fl32 = *df;
  long i4 = (long)blockIdx.x * blockDim.x + threadIdx.x;
  if (i4 >= n4) return;
  int c = (int)((i4 * 4) & (DIM - 1));
  float mu = params[6], sc = params[7];
  float4 f4 = ((const float4*)fused)[i4];
  float fv[4] = {f4.x, f4.y, f4.z, f4.w};
  float rv[4];
  #pragma unroll
  for (int j = 0; j < 4; ++j) {
    int cj = c + j;
    float r = gelu_exact((fv[j] - mu) * sc * ldf(nw, cj, fl32) + ldf(nb, cj, fl32));
    if (!isfinite(r)) r = 0.0f;
    rv[j] = r;
  }
  if (fl32) {
    ((float4*)out)[i4] = make_float4(rv[0], rv[1], rv[2], rv[3]);
  } else {
    ((ushort4*)out)[i4] = make_ushort4(f2us(rv[0]), f2us(rv[1]), f2us(rv[2]), f2us(rv[3]));
  }
}

extern "C" void kernel_launch(void* const* d_in, const int* in_sizes, int n_in,
                              void* d_out, int out_size, void* d_ws, size_t ws_size,
                              hipStream_t stream) {
  const void* x    = d_in[0];
  const int*  ei   = (const int*)d_in[1];
  const void* ew   = d_in[2];
  const void* ea   = d_in[3];
  const void* Wg   = d_in[4];
  const void* bgcn = d_in[5];
  const void* Wl   = d_in[6];
  const void* bl   = d_in[7];
  const void* Wed  = d_in[8];
  const void* att  = d_in[9];
  const void* bgat = d_in[10];
  const void* gcn_nw = d_in[11];
  const void* gcn_nb = d_in[12];
  const void* gat_nw = d_in[13];
  const void* gat_nb = d_in[14];
  const void* out_nw = d_in[15];
  const void* out_nb = d_in[16];
  const void* alpha  = d_in[17];

  const int N = in_sizes[0] / DIM;
  const int E = in_sizes[2];
  const int* src  = ei;
  const int* dstp = ei + E;
  const size_t ND = (size_t)N * DIM;
  const int nAgg = (N + 3) / 4;

  char* ws = (char*)d_ws;
  size_t o = 0;
  auto alloc = [&](size_t bytes) { size_t r = o; o += (bytes + 255) & ~(size_t)255; return r; };
  size_t o_deg    = alloc((size_t)N * 4);
  size_t o_cnt    = alloc((size_t)N * 4);
  size_t zero_end = o;                         // [0, zero_end) memset to 0
  size_t o_off    = alloc((size_t)(N + 1) * 4);
  size_t o_h      = alloc(ND * 4);             // rank (E*4) aliases head of h
  size_t o_g      = alloc(ND * 4);
  size_t o_packed = alloc(ND * 4);             // N rows x 256 ushorts
  size_t o_csr    = alloc((size_t)E * 16);
  size_t o_par    = alloc(8 * 4);
  size_t o_pA     = alloc((size_t)nAgg * 2 * 8);
  size_t o_pB     = alloc((size_t)nAgg * 2 * 8);
  size_t o_pC     = alloc((size_t)NBLK * 2 * 8);
  size_t o_flag   = alloc(4);
  size_t o_bh     = alloc((size_t)256 * 128 * 2);   // B2T hi (bf16)
  size_t o_blo    = alloc((size_t)256 * 128 * 2);   // B2T lo (bf16)
  size_t o_b2     = alloc((size_t)256 * 4);         // fused bias (f32)
  (void)ws_size; (void)n_in; (void)out_size;

  float* dis     = (float*)(ws + o_deg);
  int*   cnt     = (int*)(ws + o_cnt);
  int*   off     = (int*)(ws + o_off);
  float* h       = (float*)(ws + o_h);
  int*   rank    = (int*)(ws + o_h);           // alias: dead before mega writes h
  float* g       = (float*)(ws + o_g);
  unsigned short* packed = (unsigned short*)(ws + o_packed);
  int4*  csr     = (int4*)(ws + o_csr);
  float* params  = (float*)(ws + o_par);
  double* pA     = (double*)(ws + o_pA);
  double* pB     = (double*)(ws + o_pB);
  double* pC     = (double*)(ws + o_pC);
  int* dflag     = (int*)(ws + o_flag);
  unsigned short* Bhi = (unsigned short*)(ws + o_bh);
  unsigned short* Blo = (unsigned short*)(ws + o_blo);
  float* bias2   = (float*)(ws + o_b2);

  hipMemsetAsync(ws, 0, zero_end, stream);
  k_detect<<<1, 256, 0, stream>>>((const unsigned short*)x, (long)ND, dflag);

  k_wprep<<<128, 256, 0, stream>>>(Wg, Wl, bl, Bhi, Blo, bias2, dflag);

  int ebk = (E + 255) / 256;
  k_cnt<<<ebk, 256, 0, stream>>>(dstp, cnt, rank, E);
  k_scan<<<1, 256, 0, stream>>>(cnt, off, N, E);
  k_scatter<<<ebk, 256, 0, stream>>>(src, dstp, ew, ea, off, rank, csr, E, dflag);
  k_degdis<<<(N + 255) / 256, 256, 0, stream>>>(off, csr, dis, N);

  k_gemm_mfma<<<(N + 63) / 64, 256, 0, stream>>>(x, Bhi, Blo, bias2, packed, N, dflag);

  k_mega<<<nAgg, 256, 0, stream>>>(off, csr, dis, packed, Wed, att, bgcn, bgat,
                                   h, g, pA, pB, N, dflag);

  k_fin12<<<1, 256, 0, stream>>>(pA, pB, nAgg, alpha, params, (double)ND, dflag);

  const long n4 = (long)(ND / 4);
  k_fuse<<<NBLK, 256, 0, stream>>>(x, h, g, bgcn, bgat, gcn_nw, gcn_nb, gat_nw, gat_nb,
                                   params, pC, n4, dflag);
  k_fin3<<<1, 256, 0, stream>>>(pC, params, (double)ND);
  k_final<<<(int)((n4 + 255) / 256), 256, 0, stream>>>(h, out_nw, out_nb, params,
                                                       d_out, n4, dflag);
}

// Round 12
// 485.423 us; speedup vs baseline: 1.0560x; 1.0560x over previous
//
#include <hip/hip_runtime.h>
#include <math.h>

#define DIM 128
#define HEADS 4
#define EPS 1e-5f
#define NBLK 2048

// ---------- dtype-flex helpers ----------
__device__ __forceinline__ float us2f(unsigned short u) {
  union { unsigned int i; float f; } c; c.i = ((unsigned int)u) << 16; return c.f;
}
__device__ __forceinline__ unsigned short f2us(float f) {
  union { float ff; unsigned int i; } c; c.ff = f;
  return (unsigned short)((c.i + 0x7FFFu + ((c.i >> 16) & 1u)) >> 16);
}
__device__ __forceinline__ float ldf(const void* p, size_t i, int fl32) {
  return fl32 ? ((const float*)p)[i] : us2f(((const unsigned short*)p)[i]);
}
__device__ __forceinline__ float gelu_exact(float v) {
  return 0.5f * v * (1.0f + erff(v * 0.7071067811865475f));
}
__device__ __forceinline__ int imin(int a, int b) { return a < b ? a : b; }

// ---------- dtype detection (proven) ----------
__global__ void __launch_bounds__(256)
k_detect(const unsigned short* __restrict__ x, long n, int* __restrict__ dflag) {
  long lim = n < 8192 ? n : 8192;
  int bad = 0;
  for (long i = threadIdx.x; i < lim; i += 256) {
    float v = us2f(x[i]);
    float a = fabsf(v);
    if (!(a == 0.0f || (a > 1e-30f && a < 1e3f))) bad++;
  }
  __shared__ int sb[256];
  sb[threadIdx.x] = bad;
  __syncthreads();
  for (int off = 128; off > 0; off >>= 1) {
    if ((int)threadIdx.x < off) sb[threadIdx.x] += sb[threadIdx.x + off];
    __syncthreads();
  }
  if (threadIdx.x == 0) dflag[0] = (sb[0] > 32) ? 1 : 0;
}

// ---------- CSR construction (atomic-light; R7-proven) ----------
__global__ void k_cnt(const int* __restrict__ dst, int* __restrict__ cnt,
                      int* __restrict__ rank, int E) {
  int e = blockIdx.x * blockDim.x + threadIdx.x;
  if (e < E) rank[e] = atomicAdd(&cnt[dst[e]], 1);
}

__global__ void __launch_bounds__(256)
k_scan(const int* __restrict__ cnt, int* __restrict__ off, int N, int E) {
  __shared__ int part[256];
  int t = threadIdx.x;
  int chunk = (N + 255) / 256;
  int lo = t * chunk;
  int hi = lo + chunk; if (hi > N) hi = N;
  int s = 0;
  for (int i = lo; i < hi; ++i) s += cnt[i];
  part[t] = s;
  __syncthreads();
  if (t == 0) {
    int run = 0;
    for (int j = 0; j < 256; ++j) { int tmp = part[j]; part[j] = run; run += tmp; }
  }
  __syncthreads();
  int run = part[t];
  for (int i = lo; i < hi; ++i) { off[i] = run; run += cnt[i]; }
  if (t == 0) off[N] = E;
}

// csr record: (src, w_raw, eav, dst); nm is computed in k_mega's staging
__global__ void k_scatter(const int* __restrict__ src, const int* __restrict__ dst,
                          const void* __restrict__ ew, const void* __restrict__ ea,
                          const int* __restrict__ off, const int* __restrict__ rank,
                          int4* __restrict__ csr, int E, const int* __restrict__ df) {
  const int fl32 = *df;
  int e = blockIdx.x * blockDim.x + threadIdx.x;
  if (e >= E) return;
  int d = dst[e], s = src[e];
  int pos = off[d] + rank[e];
  float w = ldf(ew, e, fl32);
  float eav = ldf(ea, e, fl32);
  if (!isfinite(eav)) eav = 0.0f;
  csr[pos] = make_int4(s, __float_as_int(w), __float_as_int(eav), d);
}

// per-node ordered segment sum of w + fused rsqrt. csr is L2/L3-resident.
__global__ void k_degdis(const int* __restrict__ off, const int4* __restrict__ csr,
                         float* __restrict__ dis, int N) {
  int i = blockIdx.x * blockDim.x + threadIdx.x;
  if (i >= N) return;
  int b = off[i], t = off[i + 1];
  float s = 0.f;
  for (int j = b; j < t; ++j) {
    float w = __int_as_float(csr[j].y);
    if (isfinite(w)) s += w;
  }
  dis[i] = (s > 0.0f) ? rsqrtf(fmaxf(s, 1e-30f)) : 0.0f;
}

// ---------- MFMA dual-GEMM prep ----------
// B2T[col][k] bf16 col-major, columns pre-permuted to packed-row order;
// hi/lo split of B (3xBF16) keeps GEMM at ~fp32 accuracy.
__global__ void __launch_bounds__(256)
k_wprep(const void* __restrict__ Wg, const void* __restrict__ Wl,
        const void* __restrict__ bl, unsigned short* __restrict__ Bhi,
        unsigned short* __restrict__ Blo, float* __restrict__ bias2,
        const int* __restrict__ df) {
  const int fl32 = *df;
  int g = blockIdx.x * 256 + threadIdx.x;   // 0 .. 32767
  int col = g >> 7, k = g & 127;
  int t4 = col >> 2, r = col & 3;
  int wcol = t4 * 2 + (r & 1);
  float v = (r < 2) ? ldf(Wl, (size_t)k * DIM + wcol, fl32)
                    : ldf(Wg, (size_t)k * DIM + wcol, fl32);
  unsigned short hi = f2us(v);
  float lo = v - us2f(hi);
  Bhi[(size_t)col * 128 + k] = hi;
  Blo[(size_t)col * 128 + k] = f2us(lo);
  if (blockIdx.x == 0) {
    int c2 = threadIdx.x;
    int tt = c2 >> 2, rr = c2 & 3;
    bias2[c2] = (rr < 2) ? ldf(bl, tt * 2 + rr, fl32) : 0.0f;
  }
}

typedef __attribute__((ext_vector_type(8))) short short8v;          // 8 bf16
typedef __attribute__((ext_vector_type(4))) float f32x4;            // MFMA acc

// 64 rows x 256 cols per block; 4 waves. bf16 fast-path: residuals exactly
// zero -> skip lo staging AND lo MFMAs (wave-uniform branch).
__global__ void __launch_bounds__(256)
k_gemm_mfma(const void* __restrict__ x, const unsigned short* __restrict__ Bhi,
            const unsigned short* __restrict__ Blo, const float* __restrict__ bias2,
            unsigned short* __restrict__ packed, int N, const int* __restrict__ df) {
  const int fl32 = *df;
  __shared__ unsigned short Ahi[64 * 128];
  __shared__ unsigned short Alo[64 * 128];
  const int tid = threadIdx.x;
  const int r0 = blockIdx.x * 64;
  if (fl32) {
    #pragma unroll
    for (int it = 0; it < 8; ++it) {
      int i4 = tid + it * 256;
      int row = i4 >> 5, kq = i4 & 31;
      int grow = r0 + row;
      float v0 = 0.f, v1 = 0.f, v2 = 0.f, v3 = 0.f;
      if (grow < N) {
        float4 f = ((const float4*)x)[(size_t)grow * 32 + kq];
        v0 = f.x; v1 = f.y; v2 = f.z; v3 = f.w;
      }
      ushort4 hi = make_ushort4(f2us(v0), f2us(v1), f2us(v2), f2us(v3));
      ushort4 lo = make_ushort4(f2us(v0 - us2f(hi.x)), f2us(v1 - us2f(hi.y)),
                                f2us(v2 - us2f(hi.z)), f2us(v3 - us2f(hi.w)));
      int ba = (row * 256 + kq * 8) ^ ((row & 7) << 4);
      *(ushort4*)((char*)Ahi + ba) = hi;
      *(ushort4*)((char*)Alo + ba) = lo;
    }
  } else {
    #pragma unroll
    for (int it = 0; it < 8; ++it) {
      int i4 = tid + it * 256;
      int row = i4 >> 5, kq = i4 & 31;
      int grow = r0 + row;
      ushort4 hi = make_ushort4(0, 0, 0, 0);
      if (grow < N) hi = ((const ushort4*)x)[(size_t)grow * 32 + kq];
      int ba = (row * 256 + kq * 8) ^ ((row & 7) << 4);
      *(ushort4*)((char*)Ahi + ba) = hi;
    }
  }
  __syncthreads();
  const int lane = tid & 63, wid = tid >> 6;
  const int mbase = (wid >> 1) * 32;
  const int nbase = (wid & 1) * 128;
  const int lr = lane & 15, lk = lane >> 4;
  short8v ah[2][4];
  #pragma unroll
  for (int m = 0; m < 2; ++m) {
    #pragma unroll
    for (int ks = 0; ks < 4; ++ks) {
      int row = mbase + m * 16 + lr;
      int ba = (row * 256 + ks * 64 + lk * 16) ^ ((row & 7) << 4);
      ah[m][ks] = *(const short8v*)((const char*)Ahi + ba);
    }
  }
  f32x4 acc[2][8];
  const f32x4 zero = {0.0f, 0.0f, 0.0f, 0.0f};
  #pragma unroll
  for (int m = 0; m < 2; ++m)
    #pragma unroll
    for (int n = 0; n < 8; ++n) acc[m][n] = zero;
  if (fl32) {
    short8v al[2][4];
    #pragma unroll
    for (int m = 0; m < 2; ++m) {
      #pragma unroll
      for (int ks = 0; ks < 4; ++ks) {
        int row = mbase + m * 16 + lr;
        int ba = (row * 256 + ks * 64 + lk * 16) ^ ((row & 7) << 4);
        al[m][ks] = *(const short8v*)((const char*)Alo + ba);
      }
    }
    #pragma unroll
    for (int n = 0; n < 8; ++n) {
      int col = nbase + n * 16 + lr;
      const unsigned short* bh0 = Bhi + (size_t)col * 128 + lk * 8;
      const unsigned short* bl0 = Blo + (size_t)col * 128 + lk * 8;
      #pragma unroll
      for (int ks = 0; ks < 4; ++ks) {
        short8v bh  = *(const short8v*)(bh0 + ks * 32);
        short8v blv = *(const short8v*)(bl0 + ks * 32);
        acc[0][n] = __builtin_amdgcn_mfma_f32_16x16x32_bf16(ah[0][ks], bh, acc[0][n], 0, 0, 0);
        acc[1][n] = __builtin_amdgcn_mfma_f32_16x16x32_bf16(ah[1][ks], bh, acc[1][n], 0, 0, 0);
        acc[0][n] = __builtin_amdgcn_mfma_f32_16x16x32_bf16(al[0][ks], bh, acc[0][n], 0, 0, 0);
        acc[1][n] = __builtin_amdgcn_mfma_f32_16x16x32_bf16(al[1][ks], bh, acc[1][n], 0, 0, 0);
        acc[0][n] = __builtin_amdgcn_mfma_f32_16x16x32_bf16(ah[0][ks], blv, acc[0][n], 0, 0, 0);
        acc[1][n] = __builtin_amdgcn_mfma_f32_16x16x32_bf16(ah[1][ks], blv, acc[1][n], 0, 0, 0);
      }
    }
  } else {
    #pragma unroll
    for (int n = 0; n < 8; ++n) {
      int col = nbase + n * 16 + lr;
      const unsigned short* bh0 = Bhi + (size_t)col * 128 + lk * 8;
      #pragma unroll
      for (int ks = 0; ks < 4; ++ks) {
        short8v bh = *(const short8v*)(bh0 + ks * 32);
        acc[0][n] = __builtin_amdgcn_mfma_f32_16x16x32_bf16(ah[0][ks], bh, acc[0][n], 0, 0, 0);
        acc[1][n] = __builtin_amdgcn_mfma_f32_16x16x32_bf16(ah[1][ks], bh, acc[1][n], 0, 0, 0);
      }
    }
  }
  #pragma unroll
  for (int m = 0; m < 2; ++m) {
    #pragma unroll
    for (int n = 0; n < 8; ++n) {
      int col = nbase + n * 16 + lr;
      float bv = bias2[col];
      int rb = r0 + mbase + m * 16 + lk * 4;
      #pragma unroll
      for (int j = 0; j < 4; ++j) {
        int row = rb + j;
        if (row < N) {
          float v = acc[m][n][j] + bv;
          if (!isfinite(v)) v = 0.0f;
          packed[(size_t)row * 256 + col] = f2us(v);
        }
      }
    }
  }
}

// ---------- MEGA: online softmax + GCN/GAT agg + LN stats ----------
// R4-proven processing (105us) + R10 nm-fold. NEW: first window PEELED —
// its csr+dis chain is issued in the kernel prologue (before off/xd/param
// loads), and those registers DIE at the staging write (no live state across
// PROC, unlike R11's failed pipeline). ~95% of blocks have exactly one
// window, so the staging chain leaves the critical path for almost all
// blocks. Rare windows >=2 use the R10 in-loop path. Same fp32 ops/order
// => bit-identical results.
#define GATHER(sidx) (*(const ushort4*)(packed + (size_t)(sidx) * 256 + lane * 4))

#define PROC(v, m) {                                                       \
  float nm = __int_as_float((m).y), eav = __int_as_float((m).z);           \
  float vx = us2f((v).x), vy = us2f((v).y);                                \
  float z0 = xd0 + vx + eav * wd0; z0 = (z0 > 0.f) ? z0 : 0.2f * z0;       \
  float z1 = xd1 + vy + eav * wd1; z1 = (z1 > 0.f) ? z1 : 0.2f * z1;       \
  float dt = z0 * at0 + z1 * at1;                                          \
  dt += __shfl_xor(dt, 1);                                                 \
  dt += __shfl_xor(dt, 2);                                                 \
  dt += __shfl_xor(dt, 4);                                                 \
  dt += __shfl_xor(dt, 8);                                                 \
  float e = __expf(-fabsf(dt - mx));                                       \
  bool up = dt > mx;                                                       \
  float corr = up ? e : 1.0f;                                              \
  float w = up ? 1.0f : e;                                                 \
  mx = up ? dt : mx;                                                       \
  den = fmaf(den, corr, w);                                                \
  ga0 = fmaf(ga0, corr, w * vx);                                           \
  ga1 = fmaf(ga1, corr, w * vy);                                           \
  hc0 = fmaf(nm, us2f((v).z), hc0);                                        \
  hc1 = fmaf(nm, us2f((v).w), hc1);                                        \
}

#define WINDOW(base_, wlen_) {                                                        \
    int lo = beg > (base_) ? beg : (base_);                                           \
    int hiEnd = (base_) + (wlen_);                                                    \
    int hi = end < hiEnd ? end : hiEnd;                                               \
    int cnt = hi - lo;                                                                \
    if (cnt > 0) {                                                                    \
      int s0 = lo - (base_);                                                          \
      int last = s0 + cnt - 1;                                                        \
      ushort4 v0, v1, v2, v3, v4, v5, v6, v7;                                         \
      v0 = GATHER(smeta[imin(s0 + 0, last)].x);                                       \
      v1 = GATHER(smeta[imin(s0 + 1, last)].x);                                       \
      v2 = GATHER(smeta[imin(s0 + 2, last)].x);                                       \
      v3 = GATHER(smeta[imin(s0 + 3, last)].x);                                       \
      v4 = GATHER(smeta[imin(s0 + 4, last)].x);                                       \
      v5 = GATHER(smeta[imin(s0 + 5, last)].x);                                       \
      v6 = GATHER(smeta[imin(s0 + 6, last)].x);                                       \
      v7 = GATHER(smeta[imin(s0 + 7, last)].x);                                       \
      int i = 0;                                                                      \
      for (; i + 8 <= cnt; i += 8) {                                                  \
        int4 m;                                                                       \
        m = smeta[s0 + i + 0]; PROC(v0, m); v0 = GATHER(smeta[imin(s0 + i + 8,  last)].x); \
        m = smeta[s0 + i + 1]; PROC(v1, m); v1 = GATHER(smeta[imin(s0 + i + 9,  last)].x); \
        m = smeta[s0 + i + 2]; PROC(v2, m); v2 = GATHER(smeta[imin(s0 + i + 10, last)].x); \
        m = smeta[s0 + i + 3]; PROC(v3, m); v3 = GATHER(smeta[imin(s0 + i + 11, last)].x); \
        m = smeta[s0 + i + 4]; PROC(v4, m); v4 = GATHER(smeta[imin(s0 + i + 12, last)].x); \
        m = smeta[s0 + i + 5]; PROC(v5, m); v5 = GATHER(smeta[imin(s0 + i + 13, last)].x); \
        m = smeta[s0 + i + 6]; PROC(v6, m); v6 = GATHER(smeta[imin(s0 + i + 14, last)].x); \
        m = smeta[s0 + i + 7]; PROC(v7, m); v7 = GATHER(smeta[imin(s0 + i + 15, last)].x); \
      }                                                                               \
      if (i < cnt) { int4 m = smeta[s0 + i]; PROC(v0, m); ++i; }                      \
      if (i < cnt) { int4 m = smeta[s0 + i]; PROC(v1, m); ++i; }                      \
      if (i < cnt) { int4 m = smeta[s0 + i]; PROC(v2, m); ++i; }                      \
      if (i < cnt) { int4 m = smeta[s0 + i]; PROC(v3, m); ++i; }                      \
      if (i < cnt) { int4 m = smeta[s0 + i]; PROC(v4, m); ++i; }                      \
      if (i < cnt) { int4 m = smeta[s0 + i]; PROC(v5, m); ++i; }                      \
      if (i < cnt) { int4 m = smeta[s0 + i]; PROC(v6, m); ++i; }                      \
    }                                                                                 \
  }

__global__ void __launch_bounds__(256)
k_mega(const int* __restrict__ off, const int4* __restrict__ csr,
       const float* __restrict__ dis,
       const unsigned short* __restrict__ packed,
       const void* __restrict__ Wed, const void* __restrict__ att,
       const void* __restrict__ bgcn, const void* __restrict__ bgat,
       float* __restrict__ h, float* __restrict__ g,
       double* __restrict__ pA, double* __restrict__ pB, int N,
       const int* __restrict__ df) {
  const int fl32 = *df;
  const int tid = threadIdx.x;
  const int wid = tid >> 6;
  const int lane = tid & 63;
  const int n0 = blockIdx.x * 4;
  const int node = n0 + wid;
  const int c0 = lane * 2;

  const int blkBeg = off[n0];
  const int nTop = (n0 + 4 < N) ? (n0 + 4) : N;
  const int blkEnd = off[nTop];

  // ---- prologue: first window's csr + dis chain, issued FIRST ----
  int wlen0 = blkEnd - blkBeg; if (wlen0 > 256) wlen0 = 256;
  int4 cP = make_int4(0, 0, 0, 0);
  float dsP = 0.f, ddP = 0.f;
  if (tid < wlen0) {
    cP = csr[blkBeg + tid];
    dsP = dis[cP.x];
    ddP = dis[cP.w];
  }

  float wd0 = ldf(Wed, c0, fl32), wd1 = ldf(Wed, c0 + 1, fl32);
  float at0 = ldf(att, c0, fl32), at1 = ldf(att, c0 + 1, fl32);

  int beg = 0, end = 0;
  float xd0 = 0.f, xd1 = 0.f;
  if (node < N) {
    beg = off[node]; end = off[node + 1];
    ushort4 xd = *(const ushort4*)(packed + (size_t)node * 256 + lane * 4);
    xd0 = us2f(xd.x); xd1 = us2f(xd.y);
  }
  float mx = -INFINITY, den = 0.f;
  float ga0 = 0.f, ga1 = 0.f, hc0 = 0.f, hc1 = 0.f;

  __shared__ int4 smeta[256];

  // ---- peeled first window: prologue registers die at the staging write ----
  if (wlen0 > 0) {
    if (tid < wlen0) {
      float nm = dsP * __int_as_float(cP.y) * ddP;
      if (!isfinite(nm)) nm = 0.0f;
      cP.y = __float_as_int(nm);
      smeta[tid] = cP;
    }
    __syncthreads();
    WINDOW(blkBeg, wlen0);
  }
  // ---- remaining windows (rare): R10 in-loop staging path ----
  for (int base = blkBeg + 256; base < blkEnd; base += 256) {
    int wlen = blkEnd - base; if (wlen > 256) wlen = 256;
    __syncthreads();   // prior window's smeta fully consumed
    if (tid < wlen) {
      int4 c = csr[base + tid];
      float nm = dis[c.x] * __int_as_float(c.y) * dis[c.w];
      if (!isfinite(nm)) nm = 0.0f;
      c.y = __float_as_int(nm);
      smeta[tid] = c;
    }
    __syncthreads();
    WINDOW(base, wlen);
  }

  double sA = 0.0, sA2 = 0.0, sB = 0.0, sB2 = 0.0;
  if (node < N) {
    float inv = (end > beg) ? 1.0f / (den + 1e-16f) : 0.0f;
    ga0 *= inv; ga1 *= inv;
    if (!isfinite(ga0)) ga0 = 0.0f;
    if (!isfinite(ga1)) ga1 = 0.0f;
    if (!isfinite(hc0)) hc0 = 0.0f;
    if (!isfinite(hc1)) hc1 = 0.0f;
    *(float2*)(h + (size_t)node * DIM + c0) = make_float2(hc0, hc1);
    *(float2*)(g + (size_t)node * DIM + c0) = make_float2(ga0, ga1);
    float hA0 = hc0 + ldf(bgcn, c0, fl32), hA1 = hc1 + ldf(bgcn, c0 + 1, fl32);
    float gB0 = ga0 + ldf(bgat, c0, fl32), gB1 = ga1 + ldf(bgat, c0 + 1, fl32);
    sA  = (double)hA0 + (double)hA1;
    sA2 = (double)hA0 * hA0 + (double)hA1 * hA1;
    sB  = (double)gB0 + (double)gB1;
    sB2 = (double)gB0 * gB0 + (double)gB1 * gB1;
  }
  __shared__ double l1[256], l2[256], l3[256], l4[256];
  l1[threadIdx.x] = sA; l2[threadIdx.x] = sA2; l3[threadIdx.x] = sB; l4[threadIdx.x] = sB2;
  __syncthreads();
  for (int o = 128; o > 0; o >>= 1) {
    if ((int)threadIdx.x < o) {
      l1[threadIdx.x] += l1[threadIdx.x + o];
      l2[threadIdx.x] += l2[threadIdx.x + o];
      l3[threadIdx.x] += l3[threadIdx.x + o];
      l4[threadIdx.x] += l4[threadIdx.x + o];
    }
    __syncthreads();
  }
  if (threadIdx.x == 0) {
    pA[2 * blockIdx.x] = l1[0]; pA[2 * blockIdx.x + 1] = l2[0];
    pB[2 * blockIdx.x] = l3[0]; pB[2 * blockIdx.x + 1] = l4[0];
  }
}

// ---------- LN finalize / fuse / output ----------
__device__ __forceinline__ void ln_params(double S, double S2, double M, float* mu_out, float* sc_out) {
  double mu = S / M;
  double v = S2 / M - mu * mu;
  if (!(v > 0.0)) v = 0.0;
  float fmu = (float)mu;
  float sc = 1.0f / ((float)sqrt(v) + EPS);
  if (!isfinite(fmu)) fmu = 0.0f;
  if (!isfinite(sc)) sc = 0.0f;
  *mu_out = fmu; *sc_out = sc;
}

__global__ void __launch_bounds__(256)
k_fin12(const double* __restrict__ pA, const double* __restrict__ pB, int nblk,
        const void* __restrict__ alpha, float* __restrict__ params, double M,
        const int* __restrict__ df) {
  const int fl32 = *df;
  __shared__ double l1[256], l2[256], l3[256], l4[256];
  double a = 0, b = 0, c = 0, d = 0;
  for (int j = threadIdx.x; j < nblk; j += 256) {
    a += pA[2 * j]; b += pA[2 * j + 1];
    c += pB[2 * j]; d += pB[2 * j + 1];
  }
  l1[threadIdx.x] = a; l2[threadIdx.x] = b; l3[threadIdx.x] = c; l4[threadIdx.x] = d;
  __syncthreads();
  for (int off = 128; off > 0; off >>= 1) {
    if ((int)threadIdx.x < off) {
      l1[threadIdx.x] += l1[threadIdx.x + off];
      l2[threadIdx.x] += l2[threadIdx.x + off];
      l3[threadIdx.x] += l3[threadIdx.x + off];
      l4[threadIdx.x] += l4[threadIdx.x + off];
    }
    __syncthreads();
  }
  if (threadIdx.x == 0) {
    ln_params(l1[0], l2[0], M, &params[0], &params[1]);
    ln_params(l3[0], l4[0], M, &params[2], &params[3]);
    float a0 = ldf(alpha, 0, fl32), a1 = ldf(alpha, 1, fl32);
    if (!isfinite(a0)) a0 = 0.0f;
    if (!isfinite(a1)) a1 = 0.0f;
    float mx = fmaxf(a0, a1);
    float e0 = expf(a0 - mx), e1 = expf(a1 - mx);
    float inv = 1.0f / (e0 + e1);
    params[4] = e0 * inv;
    params[5] = e1 * inv;
  }
}

__global__ void __launch_bounds__(256)
k_fin3(const double* __restrict__ pC, float* __restrict__ params, double M) {
  __shared__ double l1[256], l2[256];
  double a = 0, b = 0;
  for (int j = threadIdx.x; j < NBLK; j += 256) { a += pC[2 * j]; b += pC[2 * j + 1]; }
  l1[threadIdx.x] = a; l2[threadIdx.x] = b;
  __syncthreads();
  for (int off = 128; off > 0; off >>= 1) {
    if ((int)threadIdx.x < off) {
      l1[threadIdx.x] += l1[threadIdx.x + off];
      l2[threadIdx.x] += l2[threadIdx.x + off];
    }
    __syncthreads();
  }
  if (threadIdx.x == 0) ln_params(l1[0], l2[0], M, &params[6], &params[7]);
}

// vectorized: 4 contiguous elements per thread (float4/ushort4 - G13)
__global__ void __launch_bounds__(256)
k_fuse(const void* __restrict__ x, float* h, const float* __restrict__ g,
       const void* __restrict__ b_gcn, const void* __restrict__ b_gat,
       const void* __restrict__ gcn_nw, const void* __restrict__ gcn_nb,
       const void* __restrict__ gat_nw, const void* __restrict__ gat_nb,
       const float* __restrict__ params, double* __restrict__ pC, long n4,
       const int* __restrict__ df) {
  const int fl32 = *df;
  float mu1 = params[0], sc1 = params[1], mu2 = params[2], sc2 = params[3];
  float w0 = params[4], w1 = params[5];
  double s = 0.0, s2 = 0.0;
  long stride = (long)gridDim.x * blockDim.x;
  for (long i4 = (long)blockIdx.x * blockDim.x + threadIdx.x; i4 < n4; i4 += stride) {
    int c = (int)((i4 * 4) & (DIM - 1));
    float4 hv4 = ((const float4*)h)[i4];
    float4 gv4 = ((const float4*)g)[i4];
    float xv[4];
    if (fl32) {
      float4 xf = ((const float4*)x)[i4];
      xv[0] = xf.x; xv[1] = xf.y; xv[2] = xf.z; xv[3] = xf.w;
    } else {
      ushort4 xu = ((const ushort4*)x)[i4];
      xv[0] = us2f(xu.x); xv[1] = us2f(xu.y); xv[2] = us2f(xu.z); xv[3] = us2f(xu.w);
    }
    float hv[4] = {hv4.x, hv4.y, hv4.z, hv4.w};
    float gv[4] = {gv4.x, gv4.y, gv4.z, gv4.w};
    float fo[4];
    #pragma unroll
    for (int j = 0; j < 4; ++j) {
      int cj = c + j;
      float hb = hv[j] + ldf(b_gcn, cj, fl32);
      float gb = gv[j] + ldf(b_gat, cj, fl32);
      float go = xv[j] + gelu_exact((hb - mu1) * sc1 * ldf(gcn_nw, cj, fl32) + ldf(gcn_nb, cj, fl32));
      float ao = xv[j] + gelu_exact((gb - mu2) * sc2 * ldf(gat_nw, cj, fl32) + ldf(gat_nb, cj, fl32));
      float f = w0 * go + w1 * ao;
      if (!isfinite(f)) f = 0.0f;
      fo[j] = f;
      s += f; s2 += (double)f * f;
    }
    ((float4*)h)[i4] = make_float4(fo[0], fo[1], fo[2], fo[3]);
  }
  __shared__ double ls[256], ls2[256];
  ls[threadIdx.x] = s; ls2[threadIdx.x] = s2;
  __syncthreads();
  for (int off = 128; off > 0; off >>= 1) {
    if ((int)threadIdx.x < off) {
      ls[threadIdx.x] += ls[threadIdx.x + off];
      ls2[threadIdx.x] += ls2[threadIdx.x + off];
    }
    __syncthreads();
  }
  if (threadIdx.x == 0) { pC[2 * blockIdx.x] = ls[0]; pC[2 * blockIdx.x + 1] = ls2[0]; }
}

__global__ void k_final(const float* __restrict__ fused, const void* __restrict__ nw,
                        const void* __restrict__ nb, const float* __restrict__ params,
                        void* __restrict__ out, long n4, const int* __restrict__ df) {
  const int fl32 = *df;
  long i4 = (long)blockIdx.x * blockDim.x + threadIdx.x;
  if (i4 >= n4) return;
  int c = (int)((i4 * 4) & (DIM - 1));
  float mu = params[6], sc = params[7];
  float4 f4 = ((const float4*)fused)[i4];
  float fv[4] = {f4.x, f4.y, f4.z, f4.w};
  float rv[4];
  #pragma unroll
  for (int j = 0; j < 4; ++j) {
    int cj = c + j;
    float r = gelu_exact((fv[j] - mu) * sc * ldf(nw, cj, fl32) + ldf(nb, cj, fl32));
    if (!isfinite(r)) r = 0.0f;
    rv[j] = r;
  }
  if (fl32) {
    ((float4*)out)[i4] = make_float4(rv[0], rv[1], rv[2], rv[3]);
  } else {
    ((ushort4*)out)[i4] = make_ushort4(f2us(rv[0]), f2us(rv[1]), f2us(rv[2]), f2us(rv[3]));
  }
}

extern "C" void kernel_launch(void* const* d_in, const int* in_sizes, int n_in,
                              void* d_out, int out_size, void* d_ws, size_t ws_size,
                              hipStream_t stream) {
  const void* x    = d_in[0];
  const int*  ei   = (const int*)d_in[1];
  const void* ew   = d_in[2];
  const void* ea   = d_in[3];
  const void* Wg   = d_in[4];
  const void* bgcn = d_in[5];
  const void* Wl   = d_in[6];
  const void* bl   = d_in[7];
  const void* Wed  = d_in[8];
  const void* att  = d_in[9];
  const void* bgat = d_in[10];
  const void* gcn_nw = d_in[11];
  const void* gcn_nb = d_in[12];
  const void* gat_nw = d_in[13];
  const void* gat_nb = d_in[14];
  const void* out_nw = d_in[15];
  const void* out_nb = d_in[16];
  const void* alpha  = d_in[17];

  const int N = in_sizes[0] / DIM;
  const int E = in_sizes[2];
  const int* src  = ei;
  const int* dstp = ei + E;
  const size_t ND = (size_t)N * DIM;
  const int nAgg = (N + 3) / 4;

  char* ws = (char*)d_ws;
  size_t o = 0;
  auto alloc = [&](size_t bytes) { size_t r = o; o += (bytes + 255) & ~(size_t)255; return r; };
  size_t o_deg    = alloc((size_t)N * 4);
  size_t o_cnt    = alloc((size_t)N * 4);
  size_t zero_end = o;                         // [0, zero_end) memset to 0
  size_t o_off    = alloc((size_t)(N + 1) * 4);
  size_t o_h      = alloc(ND * 4);             // rank (E*4) aliases head of h
  size_t o_g      = alloc(ND * 4);
  size_t o_packed = alloc(ND * 4);             // N rows x 256 ushorts
  size_t o_csr    = alloc((size_t)E * 16);
  size_t o_par    = alloc(8 * 4);
  size_t o_pA     = alloc((size_t)nAgg * 2 * 8);
  size_t o_pB     = alloc((size_t)nAgg * 2 * 8);
  size_t o_pC     = alloc((size_t)NBLK * 2 * 8);
  size_t o_flag   = alloc(4);
  size_t o_bh     = alloc((size_t)256 * 128 * 2);   // B2T hi (bf16)
  size_t o_blo    = alloc((size_t)256 * 128 * 2);   // B2T lo (bf16)
  size_t o_b2     = alloc((size_t)256 * 4);         // fused bias (f32)
  (void)ws_size; (void)n_in; (void)out_size;

  float* dis     = (float*)(ws + o_deg);
  int*   cnt     = (int*)(ws + o_cnt);
  int*   off     = (int*)(ws + o_off);
  float* h       = (float*)(ws + o_h);
  int*   rank    = (int*)(ws + o_h);           // alias: dead before mega writes h
  float* g       = (float*)(ws + o_g);
  unsigned short* packed = (unsigned short*)(ws + o_packed);
  int4*  csr     = (int4*)(ws + o_csr);
  float* params  = (float*)(ws + o_par);
  double* pA     = (double*)(ws + o_pA);
  double* pB     = (double*)(ws + o_pB);
  double* pC     = (double*)(ws + o_pC);
  int* dflag     = (int*)(ws + o_flag);
  unsigned short* Bhi = (unsigned short*)(ws + o_bh);
  unsigned short* Blo = (unsigned short*)(ws + o_blo);
  float* bias2   = (float*)(ws + o_b2);

  hipMemsetAsync(ws, 0, zero_end, stream);
  k_detect<<<1, 256, 0, stream>>>((const unsigned short*)x, (long)ND, dflag);

  k_wprep<<<128, 256, 0, stream>>>(Wg, Wl, bl, Bhi, Blo, bias2, dflag);

  int ebk = (E + 255) / 256;
  k_cnt<<<ebk, 256, 0, stream>>>(dstp, cnt, rank, E);
  k_scan<<<1, 256, 0, stream>>>(cnt, off, N, E);
  k_scatter<<<ebk, 256, 0, stream>>>(src, dstp, ew, ea, off, rank, csr, E, dflag);
  k_degdis<<<(N + 255) / 256, 256, 0, stream>>>(off, csr, dis, N);

  k_gemm_mfma<<<(N + 63) / 64, 256, 0, stream>>>(x, Bhi, Blo, bias2, packed, N, dflag);

  k_mega<<<nAgg, 256, 0, stream>>>(off, csr, dis, packed, Wed, att, bgcn, bgat,
                                   h, g, pA, pB, N, dflag);

  k_fin12<<<1, 256, 0, stream>>>(pA, pB, nAgg, alpha, params, (double)ND, dflag);

  const long n4 = (long)(ND / 4);
  k_fuse<<<NBLK, 256, 0, stream>>>(x, h, g, bgcn, bgat, gcn_nw, gcn_nb, gat_nw, gat_nb,
                                   params, pC, n4, dflag);
  k_fin3<<<1, 256, 0, stream>>>(pC, params, (double)ND);
  k_final<<<(int)((n4 + 255) / 256), 256, 0, stream>>>(h, out_nw, out_nb, params,
                                                       d_out, n4, dflag);
}